// Round 1
// baseline (2195.465 us; speedup 1.0000x reference)
//
#include <hip/hip_runtime.h>
#include <math.h>

// Problem constants
#define FDIM 16
#define H1DIM 64
#define H2DIM 64
#define KBINS 8
#define NBPDIM 25   // 3*K+1
#define LLAYERS 8

#define DEV __device__ __forceinline__

DEV float frcp(float x){ return __builtin_amdgcn_rcpf(x); }
DEV float fexp(float x){ return __expf(x); }
DEV float flog(float x){ return __logf(x); }

// tanh via exp; clamp keeps e^{2x} finite (tanh saturates far earlier anyway)
DEV float ftanh(float x){
  float cx = fminf(fmaxf(x, -15.f), 15.f);
  float e  = fexp(2.f * cx);
  return (e - 1.f) * frcp(e + 1.f);
}

// Rational-quadratic spline forward + log-det for one feature.
// p[0:8]=unnorm widths, p[8:16]=unnorm heights, p[16:25]=unnorm derivs.
DEV void rq_spline(const float p[25], float xv, float &y_out, float &ld_out)
{
  // softmax(widths) -> bin widths; same for heights
  float mw = p[0];
#pragma unroll
  for (int k = 1; k < 8; ++k) mw = fmaxf(mw, p[k]);
  float ew[8]; float sw = 0.f;
#pragma unroll
  for (int k = 0; k < 8; ++k){ ew[k] = fexp(p[k] - mw); sw += ew[k]; }
  float rw = frcp(sw) * 19.9992f;            // (RMAX-RMIN) - K*MIN_BIN

  float mh = p[8];
#pragma unroll
  for (int k = 1; k < 8; ++k) mh = fmaxf(mh, p[8 + k]);
  float eh[8]; float shs = 0.f;
#pragma unroll
  for (int k = 0; k < 8; ++k){ eh[k] = fexp(p[8 + k] - mh); shs += eh[k]; }
  float rh = frcp(shs) * 19.9992f;

  // derivatives: softplus(ud + log(expm1(1 - MIN_SLOPE))) + MIN_SLOPE
  float dd[9];
#pragma unroll
  for (int k = 0; k < 9; ++k){
    float v  = p[16 + k] + 0.54116666f;
    float sp = fmaxf(v, 0.f) + flog(1.f + fexp(-fabsf(v)));  // stable softplus
    dd[k] = sp + 1e-4f;
  }

  // knot positions (cumsum)
  float xpos[9], ypos[9];
  xpos[0] = -10.f; ypos[0] = -10.f;
#pragma unroll
  for (int k = 0; k < 8; ++k){
    xpos[k + 1] = xpos[k] + (ew[k] * rw + 1e-4f);
    ypos[k + 1] = ypos[k] + (eh[k] * rh + 1e-4f);
  }

  // bin index = clip(#(x >= xpos) - 1, 0, K-1)  == count over interior knots
  int idx = 0;
#pragma unroll
  for (int j = 1; j < 8; ++j) idx += (xv >= xpos[j]) ? 1 : 0;

  // gather knot data at idx via select chain (register arrays)
  float xk = xpos[0], xk1 = xpos[1], yk = ypos[0], yk1 = ypos[1], dk = dd[0], dk1 = dd[1];
#pragma unroll
  for (int j = 1; j < 8; ++j){
    bool s = (idx >= j);
    xk  = s ? xpos[j]     : xk;
    xk1 = s ? xpos[j + 1] : xk1;
    yk  = s ? ypos[j]     : yk;
    yk1 = s ? ypos[j + 1] : yk1;
    dk  = s ? dd[j]       : dk;
    dk1 = s ? dd[j + 1]   : dk1;
  }

  float bw  = xk1 - xk, bh = yk1 - yk;
  float rbw = frcp(bw);
  float s   = bh * rbw;
  float zf  = (xv - xk) * rbw;
  zf = fminf(fmaxf(zf, 0.f), 1.f);
  float z1  = 1.f - zf;
  float zz  = zf * zf, z01 = zf * z1;
  float den = s + (dk1 + dk - 2.f * s) * z01;
  float rden = frcp(den);
  float yv  = yk + bh * (s * zz + dk * z01) * rden;
  float num = dk1 * zz + 2.f * s * z01 + dk * z1 * z1;
  float ldv = flog(s * s * num * rden * rden);  // 2log(s)+log(num)-2log(den)

  bool outside = (xv <= -10.f) || (xv >= 10.f);
  y_out  = outside ? xv : yv;
  ld_out = outside ? 0.f : ldv;
}

// One coupling layer. PAR = i & 1. Features with (f+i) even are transformed;
// features with (f+i) odd feed the conditioner MLP.
template<int PAR>
DEV void do_layer(const float* __restrict__ w0, const float* __restrict__ bb0,
                  const float* __restrict__ w1, const float* __restrict__ bb1,
                  const float* __restrict__ w2, const float* __restrict__ bb2,
                  const float* __restrict__ wo, const float* __restrict__ bo,
                  const float* __restrict__ sc, const float* __restrict__ sh,
                  float (&z)[16], float &logdet)
{
  // h0 = tanh(mz @ W0 + b0); only opposite-parity features are nonzero in mz
  float h0[16];
#pragma unroll
  for (int j = 0; j < 16; ++j) h0[j] = bb0[j];
#pragma unroll
  for (int u = 0; u < 8; ++u){
    const int f = (1 - PAR) + 2 * u;
    const float v = z[f];
#pragma unroll
    for (int j = 0; j < 16; ++j) h0[j] = fmaf(v, w0[f * 16 + j], h0[j]);
  }
#pragma unroll
  for (int j = 0; j < 16; ++j) h0[j] = ftanh(h0[j]);

  // h1 = tanh(h0 @ W1 + b1)
  float h1[64];
#pragma unroll
  for (int j = 0; j < 64; ++j) h1[j] = bb1[j];
#pragma unroll
  for (int f = 0; f < 16; ++f){
    const float v = h0[f];
#pragma unroll
    for (int j = 0; j < 64; ++j) h1[j] = fmaf(v, w1[f * 64 + j], h1[j]);
  }
#pragma unroll
  for (int j = 0; j < 64; ++j) h1[j] = ftanh(h1[j]);

  // h2 = h1 @ W2 + b2   (no activation)
  float h2[64];
#pragma unroll
  for (int j = 0; j < 64; ++j) h2[j] = bb2[j];
#pragma unroll
  for (int f = 0; f < 64; ++f){
    const float v = h1[f];
#pragma unroll
    for (int j = 0; j < 64; ++j) h2[j] = fmaf(v, w2[f * 64 + j], h2[j]);
  }

  // For each transformed feature: 25 spline params = h2 @ Wout[:, f*25:(f+1)*25]
#pragma unroll
  for (int u = 0; u < 8; ++u){
    const int f = PAR + 2 * u;
    float p[25];
#pragma unroll
    for (int j = 0; j < 25; ++j) p[j] = bo[f * 25 + j];
#pragma unroll
    for (int k = 0; k < 64; ++k){
      const float v = h2[k];
#pragma unroll
      for (int j = 0; j < 25; ++j) p[j] = fmaf(v, wo[k * 400 + f * 25 + j], p[j]);
    }
    float y, ld;
    rq_spline(p, z[f], y, ld);
    z[f] = y;
    logdet += ld;
  }

  // affine: z = z*scale + shift; logdet += sum(log|scale|) (all 16 features)
#pragma unroll
  for (int j = 0; j < 16; ++j){
    logdet += flog(fabsf(sc[j]));
    z[j] = fmaf(z[j], sc[j], sh[j]);
  }
}

extern "C" __global__ void __launch_bounds__(256, 2)
flow_kernel(const float* __restrict__ x,
            const float* __restrict__ W0, const float* __restrict__ b0,
            const float* __restrict__ W1, const float* __restrict__ b1,
            const float* __restrict__ W2, const float* __restrict__ b2,
            const float* __restrict__ Wo, const float* __restrict__ bo,
            const float* __restrict__ sc, const float* __restrict__ sh,
            float* __restrict__ out, int B)
{
  int t = blockIdx.x * blockDim.x + threadIdx.x;
  if (t >= B) return;

  float z[16];
  const float4* xv = reinterpret_cast<const float4*>(x + (size_t)t * 16);
  float4 a0 = xv[0], a1 = xv[1], a2 = xv[2], a3 = xv[3];
  z[0]=a0.x; z[1]=a0.y; z[2]=a0.z; z[3]=a0.w;
  z[4]=a1.x; z[5]=a1.y; z[6]=a1.z; z[7]=a1.w;
  z[8]=a2.x; z[9]=a2.y; z[10]=a2.z; z[11]=a2.w;
  z[12]=a3.x; z[13]=a3.y; z[14]=a3.z; z[15]=a3.w;

  float logdet = 0.f;
  for (int i = LLAYERS - 1; i >= 0; --i){
    const float* w0  = W0 + i * 256;
    const float* bb0 = b0 + i * 16;
    const float* w1  = W1 + i * 1024;
    const float* bb1 = b1 + i * 64;
    const float* w2  = W2 + i * 4096;
    const float* bb2 = b2 + i * 64;
    const float* wo  = Wo + i * 25600;
    const float* bo_ = bo + i * 400;
    const float* scp = sc + i * 16;
    const float* shp = sh + i * 16;
    if (i & 1)
      do_layer<1>(w0, bb0, w1, bb1, w2, bb2, wo, bo_, scp, shp, z, logdet);
    else
      do_layer<0>(w0, bb0, w1, bb1, w2, bb2, wo, bo_, scp, shp, z, logdet);
  }

  float ss = 0.f;
#pragma unroll
  for (int j = 0; j < 16; ++j) ss = fmaf(z[j], z[j], ss);
  out[t] = -0.5f * ss - 14.7030165f + logdet;
}

extern "C" void kernel_launch(void* const* d_in, const int* in_sizes, int n_in,
                              void* d_out, int out_size, void* d_ws, size_t ws_size,
                              hipStream_t stream)
{
  const float* x    = (const float*)d_in[0];
  const float* W0   = (const float*)d_in[1];
  const float* b0   = (const float*)d_in[2];
  const float* W1   = (const float*)d_in[3];
  const float* b1   = (const float*)d_in[4];
  const float* W2   = (const float*)d_in[5];
  const float* b2   = (const float*)d_in[6];
  const float* Wout = (const float*)d_in[7];
  const float* bout = (const float*)d_in[8];
  const float* scale= (const float*)d_in[9];
  const float* shift= (const float*)d_in[10];

  int B = in_sizes[0] / FDIM;
  dim3 grid((B + 255) / 256), block(256);
  hipLaunchKernelGGL(flow_kernel, grid, block, 0, stream,
                     x, W0, b0, W1, b1, W2, b2, Wout, bout, scale, shift,
                     (float*)d_out, B);
}

// Round 2
// 1743.281 us; speedup vs baseline: 1.2594x; 1.2594x over previous
//
#include <hip/hip_runtime.h>
#include <math.h>

// Problem constants
#define FDIM 16
#define KBINS 8
#define LLAYERS 8

#define DEV __device__ __forceinline__

DEV float frcp(float x){ return __builtin_amdgcn_rcpf(x); }
DEV float fexp(float x){ return __expf(x); }
DEV float flog(float x){ return __logf(x); }

// tanh via exp; clamp keeps e^{2x} finite (tanh saturates far earlier anyway)
DEV float ftanh(float x){
  float cx = fminf(fmaxf(x, -15.f), 15.f);
  float e  = fexp(2.f * cx);
  return (e - 1.f) * frcp(e + 1.f);
}

// Rational-quadratic spline forward + log-det for one feature.
// p[0:8]=unnorm widths, p[8:16]=unnorm heights, p[16:25]=unnorm derivs.
DEV void rq_spline(const float p[25], float xv, float &y_out, float &ld_out)
{
  float mw = p[0];
#pragma unroll
  for (int k = 1; k < 8; ++k) mw = fmaxf(mw, p[k]);
  float ew[8]; float sw = 0.f;
#pragma unroll
  for (int k = 0; k < 8; ++k){ ew[k] = fexp(p[k] - mw); sw += ew[k]; }
  float rw = frcp(sw) * 19.9992f;            // (RMAX-RMIN) - K*MIN_BIN

  float mh = p[8];
#pragma unroll
  for (int k = 1; k < 8; ++k) mh = fmaxf(mh, p[8 + k]);
  float eh[8]; float shs = 0.f;
#pragma unroll
  for (int k = 0; k < 8; ++k){ eh[k] = fexp(p[8 + k] - mh); shs += eh[k]; }
  float rh = frcp(shs) * 19.9992f;

  // derivatives: softplus(ud + log(expm1(1 - MIN_SLOPE))) + MIN_SLOPE
  float dd[9];
#pragma unroll
  for (int k = 0; k < 9; ++k){
    float v  = p[16 + k] + 0.54116666f;
    float sp = fmaxf(v, 0.f) + flog(1.f + fexp(-fabsf(v)));  // stable softplus
    dd[k] = sp + 1e-4f;
  }

  float xpos[9], ypos[9];
  xpos[0] = -10.f; ypos[0] = -10.f;
#pragma unroll
  for (int k = 0; k < 8; ++k){
    xpos[k + 1] = xpos[k] + (ew[k] * rw + 1e-4f);
    ypos[k + 1] = ypos[k] + (eh[k] * rh + 1e-4f);
  }

  int idx = 0;
#pragma unroll
  for (int j = 1; j < 8; ++j) idx += (xv >= xpos[j]) ? 1 : 0;

  float xk = xpos[0], xk1 = xpos[1], yk = ypos[0], yk1 = ypos[1], dk = dd[0], dk1 = dd[1];
#pragma unroll
  for (int j = 1; j < 8; ++j){
    bool s = (idx >= j);
    xk  = s ? xpos[j]     : xk;
    xk1 = s ? xpos[j + 1] : xk1;
    yk  = s ? ypos[j]     : yk;
    yk1 = s ? ypos[j + 1] : yk1;
    dk  = s ? dd[j]       : dk;
    dk1 = s ? dd[j + 1]   : dk1;
  }

  float bw  = xk1 - xk, bh = yk1 - yk;
  float rbw = frcp(bw);
  float s   = bh * rbw;
  float zf  = (xv - xk) * rbw;
  zf = fminf(fmaxf(zf, 0.f), 1.f);
  float z1  = 1.f - zf;
  float zz  = zf * zf, z01 = zf * z1;
  float den = s + (dk1 + dk - 2.f * s) * z01;
  float rden = frcp(den);
  float yv  = yk + bh * (s * zz + dk * z01) * rden;
  float num = dk1 * zz + 2.f * s * z01 + dk * z1 * z1;
  float ldv = flog(s * s * num * rden * rden);  // 2log(s)+log(num)-2log(den)

  bool outside = (xv <= -10.f) || (xv >= 10.f);
  y_out  = outside ? xv : yv;
  ld_out = outside ? 0.f : ldv;
}

// LDS: Wout's 200 *used* columns per layer, padded per-feature to 28 floats
// so every 25-float block is 16B-aligned -> ds_read_b128.
// Layout: sWout[k*224 + u*28 + j], k=0..63 (h2 idx), u=0..7 (feature group).
#define WOUT_LDS (64 * 224)

// One coupling layer. PAR = i & 1. Features with (f+i) even are transformed;
// features with (f+i) odd feed the conditioner MLP.
template<int PAR>
DEV void do_layer(const float* __restrict__ w0, const float* __restrict__ bb0,
                  const float* __restrict__ w1, const float* __restrict__ bb1,
                  const float* __restrict__ w2, const float* __restrict__ bb2,
                  const float* __restrict__ wo, const float* __restrict__ bo,
                  const float* __restrict__ sc, const float* __restrict__ sh,
                  float (&z)[16], float &logdet,
                  float* sWout, float* sBout)
{
  // ---- cooperative staging of used Wout columns into LDS ----
  __syncthreads();   // previous layer's LDS reads must be done
  for (int idx = threadIdx.x; idx < WOUT_LDS; idx += 256){
    int k = idx / 224;
    int r = idx - k * 224;
    int u = r / 28;
    int j = r - u * 28;
    int f = PAR + 2 * u;
    sWout[idx] = (j < 25) ? wo[k * 400 + f * 25 + j] : 0.f;
  }
  if (threadIdx.x < 224){
    int u = threadIdx.x / 28, j = threadIdx.x - u * 28;
    int f = PAR + 2 * u;
    sBout[threadIdx.x] = (j < 25) ? bo[f * 25 + j] : 0.f;
  }
  __syncthreads();

  // h0 = tanh(mz @ W0 + b0); only opposite-parity features are nonzero in mz
  float h0[16];
#pragma unroll
  for (int j = 0; j < 16; ++j) h0[j] = bb0[j];
#pragma unroll
  for (int u = 0; u < 8; ++u){
    const int f = (1 - PAR) + 2 * u;
    const float v = z[f];
#pragma unroll
    for (int j = 0; j < 16; ++j) h0[j] = fmaf(v, w0[f * 16 + j], h0[j]);
  }
#pragma unroll
  for (int j = 0; j < 16; ++j) h0[j] = ftanh(h0[j]);

  // h1 = tanh(h0 @ W1 + b1)
  float h1[64];
#pragma unroll
  for (int j = 0; j < 64; ++j) h1[j] = bb1[j];
#pragma unroll
  for (int f = 0; f < 16; ++f){
    const float v = h0[f];
#pragma unroll
    for (int j = 0; j < 64; ++j) h1[j] = fmaf(v, w1[f * 64 + j], h1[j]);
  }
#pragma unroll
  for (int j = 0; j < 64; ++j) h1[j] = ftanh(h1[j]);

  // h2 = h1 @ W2 + b2   (no activation)
  float h2[64];
#pragma unroll
  for (int j = 0; j < 64; ++j) h2[j] = bb2[j];
#pragma unroll
  for (int f = 0; f < 64; ++f){
    const float v = h1[f];
#pragma unroll
    for (int j = 0; j < 64; ++j) h2[j] = fmaf(v, w2[f * 64 + j], h2[j]);
  }

  // For each transformed feature: 25 spline params from LDS-staged Wout
#pragma unroll
  for (int u = 0; u < 8; ++u){
    const int f = PAR + 2 * u;
    float p[25];
#pragma unroll
    for (int j = 0; j < 25; ++j) p[j] = sBout[u * 28 + j];
#pragma unroll
    for (int k = 0; k < 64; ++k){
      const float* wrow = &sWout[k * 224 + u * 28];
      const float v = h2[k];
#pragma unroll
      for (int j = 0; j < 25; ++j) p[j] = fmaf(v, wrow[j], p[j]);
    }
    float y, ld;
    rq_spline(p, z[f], y, ld);
    z[f] = y;
    logdet += ld;
  }

  // affine: z = z*scale + shift; logdet += sum(log|scale|) (all 16 features)
#pragma unroll
  for (int j = 0; j < 16; ++j){
    logdet += flog(fabsf(sc[j]));
    z[j] = fmaf(z[j], sc[j], sh[j]);
  }
}

extern "C" __global__ void __launch_bounds__(256, 2)
flow_kernel(const float* __restrict__ x,
            const float* __restrict__ W0, const float* __restrict__ b0,
            const float* __restrict__ W1, const float* __restrict__ b1,
            const float* __restrict__ W2, const float* __restrict__ b2,
            const float* __restrict__ Wo, const float* __restrict__ bo,
            const float* __restrict__ sc, const float* __restrict__ sh,
            float* __restrict__ out, int B)
{
  __shared__ float sWout[WOUT_LDS];   // 56 KB
  __shared__ float sBout[224];

  int t = blockIdx.x * blockDim.x + threadIdx.x;
  // Grid is exact (B divisible by 256); clamp instead of early-return so all
  // threads reach the __syncthreads() inside do_layer.
  int ts = (t < B) ? t : (B - 1);

  float z[16];
  const float4* xv = reinterpret_cast<const float4*>(x + (size_t)ts * 16);
  float4 a0 = xv[0], a1 = xv[1], a2 = xv[2], a3 = xv[3];
  z[0]=a0.x; z[1]=a0.y; z[2]=a0.z; z[3]=a0.w;
  z[4]=a1.x; z[5]=a1.y; z[6]=a1.z; z[7]=a1.w;
  z[8]=a2.x; z[9]=a2.y; z[10]=a2.z; z[11]=a2.w;
  z[12]=a3.x; z[13]=a3.y; z[14]=a3.z; z[15]=a3.w;

  float logdet = 0.f;
  for (int i = LLAYERS - 1; i >= 0; --i){
    const float* w0  = W0 + i * 256;
    const float* bb0 = b0 + i * 16;
    const float* w1  = W1 + i * 1024;
    const float* bb1 = b1 + i * 64;
    const float* w2  = W2 + i * 4096;
    const float* bb2 = b2 + i * 64;
    const float* wo  = Wo + i * 25600;
    const float* bo_ = bo + i * 400;
    const float* scp = sc + i * 16;
    const float* shp = sh + i * 16;
    if (i & 1)
      do_layer<1>(w0, bb0, w1, bb1, w2, bb2, wo, bo_, scp, shp, z, logdet, sWout, sBout);
    else
      do_layer<0>(w0, bb0, w1, bb1, w2, bb2, wo, bo_, scp, shp, z, logdet, sWout, sBout);
  }

  float ss = 0.f;
#pragma unroll
  for (int j = 0; j < 16; ++j) ss = fmaf(z[j], z[j], ss);
  if (t < B) out[t] = -0.5f * ss - 14.7030165f + logdet;
}

extern "C" void kernel_launch(void* const* d_in, const int* in_sizes, int n_in,
                              void* d_out, int out_size, void* d_ws, size_t ws_size,
                              hipStream_t stream)
{
  const float* x    = (const float*)d_in[0];
  const float* W0   = (const float*)d_in[1];
  const float* b0   = (const float*)d_in[2];
  const float* W1   = (const float*)d_in[3];
  const float* b1   = (const float*)d_in[4];
  const float* W2   = (const float*)d_in[5];
  const float* b2   = (const float*)d_in[6];
  const float* Wout = (const float*)d_in[7];
  const float* bout = (const float*)d_in[8];
  const float* scale= (const float*)d_in[9];
  const float* shift= (const float*)d_in[10];

  int B = in_sizes[0] / FDIM;
  dim3 grid((B + 255) / 256), block(256);
  hipLaunchKernelGGL(flow_kernel, grid, block, 0, stream,
                     x, W0, b0, W1, b1, W2, b2, Wout, bout, scale, shift,
                     (float*)d_out, B);
}

// Round 4
// 269.670 us; speedup vs baseline: 8.1413x; 6.4645x over previous
//
#include <hip/hip_runtime.h>
#include <math.h>

typedef _Float16 f16;
typedef _Float16 half8 __attribute__((ext_vector_type(8)));
typedef float f32x16 __attribute__((ext_vector_type(16)));

#define DEV __device__ __forceinline__

// ---------------- workspace layout (bytes) ----------------
// fp16 B-fragment packs for v_mfma_f32_32x32x16_f16:
//   frag = 1024 B = 64 lanes x 8 f16;  B[k][n]: n = lane&31, k = (lane>>5)*8 + j
#define W1F_OFF 0        // [L][nt2]      : 16 frags  = 16 KB
#define W2F_OFF 16384    // [L][kt4][nt2] : 64 frags  = 64 KB
#define WOF_OFF 81920    // [L][u8][kt4]  : 256 frags = 256 KB (used cols, 32-padded per feature)
#define BOF_OFF 344064   // [L][u8][32] fp32 bias for used cols = 8 KB

// ---------------- LDS layout (bytes, per block of 256 samples) -------------
#define H0_OFF    0       // [256][48]  : 16 f16/sample (stride 48 kills b128 conflicts)
#define H0_STRIDE 48
#define H_OFF     12288   // [256][144] : 64 f16/sample (128+16 pad -> 4-way max)
#define H_STRIDE  144
#define P_OFF     49152   // [256][116] : 29 fp32/sample (stride 29 dwords: conflict-free b32)
#define P_STRIDE  116
#define LDS_BYTES 78848

DEV float frcp(float x){ return __builtin_amdgcn_rcpf(x); }
DEV float fexp(float x){ return __expf(x); }
DEV float flog(float x){ return __logf(x); }

DEV float ftanh(float x){
  float cx = fminf(fmaxf(x, -15.f), 15.f);
  float e  = fexp(2.f * cx);
  return (e - 1.f) * frcp(e + 1.f);
}

DEV f32x16 zero16(){ f32x16 r;
#pragma unroll
  for (int i = 0; i < 16; ++i) r[i] = 0.f;
  return r; }

// Rational-quadratic spline forward + log-det (fp32, per-thread).
DEV void rq_spline(const float p[25], float xv, float &y_out, float &ld_out)
{
  float mw = p[0];
#pragma unroll
  for (int k = 1; k < 8; ++k) mw = fmaxf(mw, p[k]);
  float ew[8]; float sw = 0.f;
#pragma unroll
  for (int k = 0; k < 8; ++k){ ew[k] = fexp(p[k] - mw); sw += ew[k]; }
  float rw = frcp(sw) * 19.9992f;

  float mh = p[8];
#pragma unroll
  for (int k = 1; k < 8; ++k) mh = fmaxf(mh, p[8 + k]);
  float eh[8]; float shs = 0.f;
#pragma unroll
  for (int k = 0; k < 8; ++k){ eh[k] = fexp(p[8 + k] - mh); shs += eh[k]; }
  float rh = frcp(shs) * 19.9992f;

  float dd[9];
#pragma unroll
  for (int k = 0; k < 9; ++k){
    float v  = p[16 + k] + 0.54116666f;
    float sp = fmaxf(v, 0.f) + flog(1.f + fexp(-fabsf(v)));
    dd[k] = sp + 1e-4f;
  }

  float xpos[9], ypos[9];
  xpos[0] = -10.f; ypos[0] = -10.f;
#pragma unroll
  for (int k = 0; k < 8; ++k){
    xpos[k + 1] = xpos[k] + (ew[k] * rw + 1e-4f);
    ypos[k + 1] = ypos[k] + (eh[k] * rh + 1e-4f);
  }

  int idx = 0;
#pragma unroll
  for (int j = 1; j < 8; ++j) idx += (xv >= xpos[j]) ? 1 : 0;

  float xk = xpos[0], xk1 = xpos[1], yk = ypos[0], yk1 = ypos[1], dk = dd[0], dk1 = dd[1];
#pragma unroll
  for (int j = 1; j < 8; ++j){
    bool s = (idx >= j);
    xk  = s ? xpos[j]     : xk;
    xk1 = s ? xpos[j + 1] : xk1;
    yk  = s ? ypos[j]     : yk;
    yk1 = s ? ypos[j + 1] : yk1;
    dk  = s ? dd[j]       : dk;
    dk1 = s ? dd[j + 1]   : dk1;
  }

  float bw  = xk1 - xk, bh = yk1 - yk;
  float rbw = frcp(bw);
  float s   = bh * rbw;
  float zf  = (xv - xk) * rbw;
  zf = fminf(fmaxf(zf, 0.f), 1.f);
  float z1  = 1.f - zf;
  float zz  = zf * zf, z01 = zf * z1;
  float den = s + (dk1 + dk - 2.f * s) * z01;
  float rden = frcp(den);
  float yv  = yk + bh * (s * zz + dk * z01) * rden;
  float num = dk1 * zz + 2.f * s * z01 + dk * z1 * z1;
  float ldv = flog(s * s * num * rden * rden);

  bool outside = (xv <= -10.f) || (xv >= 10.f);
  y_out  = outside ? xv : yv;
  ld_out = outside ? 0.f : ldv;
}

// ---------------- prep kernel: pack fp16 B-fragments into ws ----------------
extern "C" __global__ void __launch_bounds__(256)
prep_kernel(const float* __restrict__ W1, const float* __restrict__ W2,
            const float* __restrict__ Wo, const float* __restrict__ bout,
            char* __restrict__ ws)
{
  int tid = blockIdx.x * 256 + threadIdx.x;
  if (tid < 1024){                       // W1 frags: [L][nt2]
    int fi = tid >> 6, lane = tid & 63;
    int l = fi >> 1, nt = fi & 1;
    int n = nt * 32 + (lane & 31), khi = lane >> 5;
    half8 h;
#pragma unroll
    for (int j = 0; j < 8; ++j){ int k = khi * 8 + j; h[j] = (f16)W1[l * 1024 + k * 64 + n]; }
    *(half8*)(ws + W1F_OFF + fi * 1024 + lane * 16) = h;
  } else if (tid < 5120){                // W2 frags: [L][kt4][nt2]
    int idx = tid - 1024;
    int fi = idx >> 6, lane = idx & 63;
    int l = fi >> 3, kt = (fi >> 1) & 3, nt = fi & 1;
    int n = nt * 32 + (lane & 31), khi = lane >> 5;
    half8 h;
#pragma unroll
    for (int j = 0; j < 8; ++j){ int k = kt * 16 + khi * 8 + j; h[j] = (f16)W2[l * 4096 + k * 64 + n]; }
    *(half8*)(ws + W2F_OFF + fi * 1024 + lane * 16) = h;
  } else if (tid < 21504){               // Wout used-col frags: [L][u8][kt4]
    int idx = tid - 5120;
    int fi = idx >> 6, lane = idx & 63;
    int l = fi >> 5, u = (fi >> 2) & 7, kt = fi & 3;
    int f = (l & 1) + 2 * u;
    int c = lane & 31, khi = lane >> 5;
    half8 h;
#pragma unroll
    for (int j = 0; j < 8; ++j){
      int k = kt * 16 + khi * 8 + j;
      float v = (c < 25) ? Wo[l * 25600 + k * 400 + f * 25 + c] : 0.f;
      h[j] = (f16)v;
    }
    *(half8*)(ws + WOF_OFF + fi * 1024 + lane * 16) = h;
  } else if (tid < 23552){               // bout used cols: [L][u8][32] fp32
    int idx = tid - 21504;
    int l = idx >> 8, u = (idx >> 5) & 7, c = idx & 31;
    int f = (l & 1) + 2 * u;
    float v = (c < 25) ? bout[l * 400 + f * 25 + c] : 0.f;
    ((float*)(ws + BOF_OFF))[idx] = v;
  }
}

// ---------------- one coupling layer (all LDS traffic wave-private) --------
template<int PAR>
DEV void layer_mfma(int l,
                    const float* __restrict__ W0, const float* __restrict__ b0,
                    const float* __restrict__ b1v, const float* __restrict__ b2v,
                    const float* __restrict__ scv, const float* __restrict__ shv,
                    const char* __restrict__ ws, char* lds,
                    float (&z)[16], float &logdet,
                    int t, int lane, int wv, int ln31, int khi)
{
  const float* w0  = W0 + l * 256;
  const float* bb0 = b0 + l * 16;
  const int rowbase = khi * 4;     // C/D layout: row = (i&3)+8*(i>>2)+4*(lane>>5)

  // ---- h0 = tanh(mz @ W0 + b0), per-thread VALU ----
  float h0[16];
#pragma unroll
  for (int j = 0; j < 16; ++j) h0[j] = bb0[j];
#pragma unroll
  for (int u = 0; u < 8; ++u){
    const int f = (1 - PAR) + 2 * u;
    const float v = z[f];
#pragma unroll
    for (int j = 0; j < 16; ++j) h0[j] = fmaf(v, w0[f * 16 + j], h0[j]);
  }
  {
    half8 lo, hi;
#pragma unroll
    for (int j = 0; j < 8; ++j){ lo[j] = (f16)ftanh(h0[j]); hi[j] = (f16)ftanh(h0[8 + j]); }
    *(half8*)(lds + H0_OFF + t * H0_STRIDE)      = lo;
    *(half8*)(lds + H0_OFF + t * H0_STRIDE + 16) = hi;
  }

  // ---- W1: h1 = tanh(h0 @ W1 + b1) via MFMA ----
  half8 a0[2];
#pragma unroll
  for (int mt = 0; mt < 2; ++mt){
    int s = wv * 64 + mt * 32 + ln31;
    a0[mt] = *(const half8*)(lds + H0_OFF + s * H0_STRIDE + khi * 16);
  }
  f32x16 d1[2][2];
#pragma unroll
  for (int mt = 0; mt < 2; ++mt)
#pragma unroll
    for (int nt = 0; nt < 2; ++nt) d1[mt][nt] = zero16();
  const half8* W1F = (const half8*)(ws + W1F_OFF);
#pragma unroll
  for (int nt = 0; nt < 2; ++nt){
    half8 bf = W1F[(l * 2 + nt) * 64 + lane];
#pragma unroll
    for (int mt = 0; mt < 2; ++mt)
      d1[mt][nt] = __builtin_amdgcn_mfma_f32_32x32x16_f16(a0[mt], bf, d1[mt][nt], 0, 0, 0);
  }
  float bias1[2];
#pragma unroll
  for (int nt = 0; nt < 2; ++nt) bias1[nt] = b1v[l * 64 + nt * 32 + ln31];
#pragma unroll
  for (int mt = 0; mt < 2; ++mt)
#pragma unroll
    for (int nt = 0; nt < 2; ++nt)
#pragma unroll
      for (int i = 0; i < 16; ++i){
        int row = (i & 3) + 8 * (i >> 2) + rowbase;
        int s = wv * 64 + mt * 32 + row;
        float v = ftanh(d1[mt][nt][i] + bias1[nt]);
        *(f16*)(lds + H_OFF + s * H_STRIDE + (nt * 32 + ln31) * 2) = (f16)v;
      }

  // ---- W2: h2 = h1 @ W2 + b2 via MFMA ----
  half8 a1[2][4];
#pragma unroll
  for (int mt = 0; mt < 2; ++mt){
    int s = wv * 64 + mt * 32 + ln31;
#pragma unroll
    for (int kt = 0; kt < 4; ++kt)
      a1[mt][kt] = *(const half8*)(lds + H_OFF + s * H_STRIDE + kt * 32 + khi * 16);
  }
  f32x16 d2[2][2];
#pragma unroll
  for (int mt = 0; mt < 2; ++mt)
#pragma unroll
    for (int nt = 0; nt < 2; ++nt) d2[mt][nt] = zero16();
  const half8* W2F = (const half8*)(ws + W2F_OFF);
#pragma unroll
  for (int kt = 0; kt < 4; ++kt)
#pragma unroll
    for (int nt = 0; nt < 2; ++nt){
      half8 bf = W2F[((l * 4 + kt) * 2 + nt) * 64 + lane];
#pragma unroll
      for (int mt = 0; mt < 2; ++mt)
        d2[mt][nt] = __builtin_amdgcn_mfma_f32_32x32x16_f16(a1[mt][kt], bf, d2[mt][nt], 0, 0, 0);
    }
  float bias2[2];
#pragma unroll
  for (int nt = 0; nt < 2; ++nt) bias2[nt] = b2v[l * 64 + nt * 32 + ln31];
#pragma unroll
  for (int mt = 0; mt < 2; ++mt)
#pragma unroll
    for (int nt = 0; nt < 2; ++nt)
#pragma unroll
      for (int i = 0; i < 16; ++i){
        int row = (i & 3) + 8 * (i >> 2) + rowbase;
        int s = wv * 64 + mt * 32 + row;
        float v = d2[mt][nt][i] + bias2[nt];
        *(f16*)(lds + H_OFF + s * H_STRIDE + (nt * 32 + ln31) * 2) = (f16)v;
      }

  // ---- h2 A-fragments (reused across all 8 features) ----
  half8 a2[2][4];
#pragma unroll
  for (int mt = 0; mt < 2; ++mt){
    int s = wv * 64 + mt * 32 + ln31;
#pragma unroll
    for (int kt = 0; kt < 4; ++kt)
      a2[mt][kt] = *(const half8*)(lds + H_OFF + s * H_STRIDE + kt * 32 + khi * 16);
  }

  // ---- per-feature: p = h2 @ Wout_cols + bout, transpose via LDS, spline ----
  const half8* WOF = (const half8*)(ws + WOF_OFF);
  const float* BOF = (const float*)(ws + BOF_OFF);
#pragma unroll 1
  for (int u = 0; u < 8; ++u){
    const int f = PAR + 2 * u;
    f32x16 dp[2];
    dp[0] = zero16(); dp[1] = zero16();
#pragma unroll
    for (int kt = 0; kt < 4; ++kt){
      half8 bf = WOF[((l * 8 + u) * 4 + kt) * 64 + lane];
#pragma unroll
      for (int mt = 0; mt < 2; ++mt)
        dp[mt] = __builtin_amdgcn_mfma_f32_32x32x16_f16(a2[mt][kt], bf, dp[mt], 0, 0, 0);
    }
    float biasp = BOF[(l * 8 + u) * 32 + ln31];
    if (ln31 < 25){
#pragma unroll
      for (int mt = 0; mt < 2; ++mt)
#pragma unroll
        for (int i = 0; i < 16; ++i){
          int row = (i & 3) + 8 * (i >> 2) + rowbase;
          int s = wv * 64 + mt * 32 + row;
          *(float*)(lds + P_OFF + s * P_STRIDE + ln31 * 4) = dp[mt][i] + biasp;
        }
    }
    float p[25];
#pragma unroll
    for (int j = 0; j < 25; ++j)
      p[j] = *(const float*)(lds + P_OFF + t * P_STRIDE + j * 4);
    float y, ld;
    rq_spline(p, z[f], y, ld);
    z[f] = y;
    logdet += ld;
  }

  // ---- affine ----
  const float* scp = scv + l * 16;
  const float* shp = shv + l * 16;
#pragma unroll
  for (int j = 0; j < 16; ++j){
    logdet += flog(fabsf(scp[j]));
    z[j] = fmaf(z[j], scp[j], shp[j]);
  }
}

extern "C" __global__ void __launch_bounds__(256, 2)
flow_kernel(const float* __restrict__ x,
            const float* __restrict__ W0, const float* __restrict__ b0,
            const float* __restrict__ b1v, const float* __restrict__ b2v,
            const float* __restrict__ scv, const float* __restrict__ shv,
            const char* __restrict__ ws, float* __restrict__ out, int B)
{
  extern __shared__ char lds[];
  const int t    = threadIdx.x;
  const int lane = t & 63;
  const int wv   = t >> 6;
  const int ln31 = lane & 31;
  const int khi  = lane >> 5;
  const int g    = blockIdx.x * 256 + t;

  float z[16];
  const float4* xv = reinterpret_cast<const float4*>(x + (size_t)g * 16);
  float4 a0 = xv[0], a1 = xv[1], a2 = xv[2], a3 = xv[3];
  z[0]=a0.x; z[1]=a0.y; z[2]=a0.z; z[3]=a0.w;
  z[4]=a1.x; z[5]=a1.y; z[6]=a1.z; z[7]=a1.w;
  z[8]=a2.x; z[9]=a2.y; z[10]=a2.z; z[11]=a2.w;
  z[12]=a3.x; z[13]=a3.y; z[14]=a3.z; z[15]=a3.w;

  float logdet = 0.f;
  for (int l = 7; l >= 0; --l){
    if (l & 1) layer_mfma<1>(l, W0, b0, b1v, b2v, scv, shv, ws, lds, z, logdet, t, lane, wv, ln31, khi);
    else       layer_mfma<0>(l, W0, b0, b1v, b2v, scv, shv, ws, lds, z, logdet, t, lane, wv, ln31, khi);
  }

  float ss = 0.f;
#pragma unroll
  for (int j = 0; j < 16; ++j) ss = fmaf(z[j], z[j], ss);
  out[g] = -0.5f * ss - 14.7030165f + logdet;
}

extern "C" void kernel_launch(void* const* d_in, const int* in_sizes, int n_in,
                              void* d_out, int out_size, void* d_ws, size_t ws_size,
                              hipStream_t stream)
{
  const float* x    = (const float*)d_in[0];
  const float* W0   = (const float*)d_in[1];
  const float* b0   = (const float*)d_in[2];
  const float* W1   = (const float*)d_in[3];
  const float* b1   = (const float*)d_in[4];
  const float* W2   = (const float*)d_in[5];
  const float* b2   = (const float*)d_in[6];
  const float* Wout = (const float*)d_in[7];
  const float* bout = (const float*)d_in[8];
  const float* scale= (const float*)d_in[9];
  const float* shift= (const float*)d_in[10];

  int B = in_sizes[0] / 16;

  hipLaunchKernelGGL(prep_kernel, dim3(92), dim3(256), 0, stream,
                     W1, W2, Wout, bout, (char*)d_ws);

  hipLaunchKernelGGL(flow_kernel, dim3(B / 256), dim3(256), LDS_BYTES, stream,
                     x, W0, b0, b1, b2, scale, shift,
                     (const char*)d_ws, (float*)d_out, B);
}

// Round 5
// 212.620 us; speedup vs baseline: 10.3258x; 1.2683x over previous
//
#include <hip/hip_runtime.h>
#include <math.h>

typedef _Float16 f16;
typedef _Float16 half8 __attribute__((ext_vector_type(8)));
typedef float f32x16 __attribute__((ext_vector_type(16)));

#define DEV __device__ __forceinline__

// ---------------- workspace layout (bytes) ----------------
// fp16 B-fragment packs for v_mfma_f32_32x32x16_f16:
//   frag = 1024 B = 64 lanes x 8 f16;  B[k][n]: n = lane&31, k = (lane>>5)*8 + j
#define W1F_OFF 0        // [L][nt2]      : 16 frags  = 16 KB
#define W2F_OFF 16384    // [L][kt4][nt2] : 64 frags  = 64 KB
#define WOF_OFF 81920    // [L][u8][kt4]  : 256 frags = 256 KB (used cols, 32-padded)
#define BOF_OFF 344064   // [L][u8][32] fp32 bias for used cols = 8 KB
#define SUMLOG_OFF 352256 // 1 fp32: sum over all layers/features of log|scale|

// ---------------- LDS layout (bytes, per block of 256 samples) -------------
#define H0_OFF    0       // [256][48]  : 16 f16/sample
#define H0_STRIDE 48
#define H_OFF     12288   // [256][144] : 64 f16/sample (128+16 pad)
#define H_STRIDE  144
#define P_OFF     49152   // [256][116] : 29 fp32/sample (stride 29 dwords, conflict-free b32)
#define P_STRIDE  116
#define LDS_BYTES 78848

DEV float frcp(float x){ return __builtin_amdgcn_rcpf(x); }
DEV float fexp(float x){ return __expf(x); }
DEV float flog(float x){ return __logf(x); }

DEV float ftanh(float x){
  float cx = fminf(fmaxf(x, -15.f), 15.f);
  float e  = fexp(2.f * cx);
  return (e - 1.f) * frcp(e + 1.f);
}

DEV f32x16 zero16(){ f32x16 r;
#pragma unroll
  for (int i = 0; i < 16; ++i) r[i] = 0.f;
  return r; }

// Rational-quadratic spline forward + log-det (fp32, per-thread).
// Op-diet version: no softmax max-sub (|p| small), only 2 softplus (at idx,
// idx+1), masked partial sum for y-knot instead of full cumsum+gather.
DEV void rq_spline(const float p[25], float xv, float &y_out, float &ld_out)
{
  // widths
  float ew[8]; float sw = 0.f;
#pragma unroll
  for (int k = 0; k < 8; ++k){ ew[k] = fexp(p[k]); sw += ew[k]; }
  float rw = frcp(sw) * 19.9992f;           // (RMAX-RMIN) - K*MIN_BIN

  float xpos[9];
  xpos[0] = -10.f;
#pragma unroll
  for (int k = 0; k < 8; ++k) xpos[k + 1] = xpos[k] + fmaf(ew[k], rw, 1e-4f);

  int idx = 0;
#pragma unroll
  for (int j = 1; j < 8; ++j) idx += (xv >= xpos[j]) ? 1 : 0;

  float xk = xpos[0], ewk = ew[0];
#pragma unroll
  for (int j = 1; j < 8; ++j){
    bool sel = (idx >= j);
    xk  = sel ? xpos[j] : xk;
    ewk = sel ? ew[j]   : ewk;
  }
  float bw = fmaf(ewk, rw, 1e-4f);

  // heights: only need total sum, partial sum below idx, and eh[idx]
  float eh[8]; float shs = 0.f;
#pragma unroll
  for (int k = 0; k < 8; ++k){ eh[k] = fexp(p[8 + k]); shs += eh[k]; }
  float rh = frcp(shs) * 19.9992f;

  float S = 0.f, ehk = eh[0];
#pragma unroll
  for (int k = 1; k < 8; ++k){
    bool sel = (idx >= k);
    S   += sel ? eh[k - 1] : 0.f;
    ehk  = sel ? eh[k]     : ehk;
  }
  float yk = fmaf(S, rh, fmaf((float)idx, 1e-4f, -10.f));
  float bh = fmaf(ehk, rh, 1e-4f);

  // derivatives: softplus only at idx and idx+1
  float uA = p[16], uB = p[17];
#pragma unroll
  for (int j = 1; j < 8; ++j){
    bool sel = (idx >= j);
    uA = sel ? p[16 + j] : uA;
    uB = sel ? p[17 + j] : uB;
  }
  float vA = uA + 0.54116666f;
  float dk  = fmaxf(vA, 0.f) + flog(1.f + fexp(-fabsf(vA))) + 1e-4f;
  float vB = uB + 0.54116666f;
  float dk1 = fmaxf(vB, 0.f) + flog(1.f + fexp(-fabsf(vB))) + 1e-4f;

  float rbw = frcp(bw);
  float s   = bh * rbw;
  float zf  = fminf(fmaxf((xv - xk) * rbw, 0.f), 1.f);
  float z1  = 1.f - zf;
  float zz  = zf * zf, z01 = zf * z1;
  float den = s + (dk1 + dk - 2.f * s) * z01;
  float rden = frcp(den);
  float yv  = yk + bh * (s * zz + dk * z01) * rden;
  float num = dk1 * zz + 2.f * s * z01 + dk * z1 * z1;
  float ldv = flog(s * s * num * rden * rden);

  bool outside = (xv <= -10.f) || (xv >= 10.f);
  y_out  = outside ? xv : yv;
  ld_out = outside ? 0.f : ldv;
}

// ---------------- prep kernel: pack fp16 B-fragments into ws ----------------
extern "C" __global__ void __launch_bounds__(256)
prep_kernel(const float* __restrict__ W1, const float* __restrict__ W2,
            const float* __restrict__ Wo, const float* __restrict__ bout,
            const float* __restrict__ scale, char* __restrict__ ws)
{
  int tid = blockIdx.x * 256 + threadIdx.x;
  if (tid < 1024){                       // W1 frags: [L][nt2]
    int fi = tid >> 6, lane = tid & 63;
    int l = fi >> 1, nt = fi & 1;
    int n = nt * 32 + (lane & 31), khi = lane >> 5;
    half8 h;
#pragma unroll
    for (int j = 0; j < 8; ++j){ int k = khi * 8 + j; h[j] = (f16)W1[l * 1024 + k * 64 + n]; }
    *(half8*)(ws + W1F_OFF + fi * 1024 + lane * 16) = h;
  } else if (tid < 5120){                // W2 frags: [L][kt4][nt2]
    int idx = tid - 1024;
    int fi = idx >> 6, lane = idx & 63;
    int l = fi >> 3, kt = (fi >> 1) & 3, nt = fi & 1;
    int n = nt * 32 + (lane & 31), khi = lane >> 5;
    half8 h;
#pragma unroll
    for (int j = 0; j < 8; ++j){ int k = kt * 16 + khi * 8 + j; h[j] = (f16)W2[l * 4096 + k * 64 + n]; }
    *(half8*)(ws + W2F_OFF + fi * 1024 + lane * 16) = h;
  } else if (tid < 21504){               // Wout used-col frags: [L][u8][kt4]
    int idx = tid - 5120;
    int fi = idx >> 6, lane = idx & 63;
    int l = fi >> 5, u = (fi >> 2) & 7, kt = fi & 3;
    int f = (l & 1) + 2 * u;
    int c = lane & 31, khi = lane >> 5;
    half8 h;
#pragma unroll
    for (int j = 0; j < 8; ++j){
      int k = kt * 16 + khi * 8 + j;
      float v = (c < 25) ? Wo[l * 25600 + k * 400 + f * 25 + c] : 0.f;
      h[j] = (f16)v;
    }
    *(half8*)(ws + WOF_OFF + fi * 1024 + lane * 16) = h;
  } else if (tid < 23552){               // bout used cols: [L][u8][32] fp32
    int idx = tid - 21504;
    int l = idx >> 8, u = (idx >> 5) & 7, c = idx & 31;
    int f = (l & 1) + 2 * u;
    float v = (c < 25) ? bout[l * 400 + f * 25 + c] : 0.f;
    ((float*)(ws + BOF_OFF))[idx] = v;
  } else if (tid == 23552){              // sum of log|scale| over all layers
    float acc = 0.f;
    for (int i = 0; i < 128; ++i) acc += logf(fabsf(scale[i]));
    *(float*)(ws + SUMLOG_OFF) = acc;
  }
}

// ---------------- one coupling layer (all LDS traffic wave-private) --------
template<int PAR>
DEV void layer_mfma(int l,
                    const float* __restrict__ W0, const float* __restrict__ b0,
                    const float* __restrict__ b1v, const float* __restrict__ b2v,
                    const float* __restrict__ scv, const float* __restrict__ shv,
                    const char* __restrict__ ws, char* lds,
                    float (&z)[16], float &logdet,
                    int t, int lane, int wv, int ln31, int khi)
{
  const float* w0  = W0 + l * 256;
  const float* bb0 = b0 + l * 16;
  const int rowbase = khi * 4;     // C/D layout: row = (i&3)+8*(i>>2)+4*(lane>>5)

  // ---- hoisted weight-fragment loads (latency hidden behind h0 VALU) ----
  const half8* W1F = (const half8*)(ws + W1F_OFF);
  const half8* W2F = (const half8*)(ws + W2F_OFF);
  half8 w1f[2];
#pragma unroll
  for (int nt = 0; nt < 2; ++nt) w1f[nt] = W1F[(l * 2 + nt) * 64 + lane];
  half8 w2f[8];
#pragma unroll
  for (int kt = 0; kt < 4; ++kt)
#pragma unroll
    for (int nt = 0; nt < 2; ++nt)
      w2f[kt * 2 + nt] = W2F[((l * 4 + kt) * 2 + nt) * 64 + lane];
  float bias1[2], bias2[2];
#pragma unroll
  for (int nt = 0; nt < 2; ++nt){
    bias1[nt] = b1v[l * 64 + nt * 32 + ln31];
    bias2[nt] = b2v[l * 64 + nt * 32 + ln31];
  }

  // ---- h0 = tanh(mz @ W0 + b0), per-thread VALU ----
  float h0[16];
#pragma unroll
  for (int j = 0; j < 16; ++j) h0[j] = bb0[j];
#pragma unroll
  for (int u = 0; u < 8; ++u){
    const int f = (1 - PAR) + 2 * u;
    const float v = z[f];
#pragma unroll
    for (int j = 0; j < 16; ++j) h0[j] = fmaf(v, w0[f * 16 + j], h0[j]);
  }
  {
    half8 lo, hi;
#pragma unroll
    for (int j = 0; j < 8; ++j){ lo[j] = (f16)ftanh(h0[j]); hi[j] = (f16)ftanh(h0[8 + j]); }
    *(half8*)(lds + H0_OFF + t * H0_STRIDE)      = lo;
    *(half8*)(lds + H0_OFF + t * H0_STRIDE + 16) = hi;
  }

  // ---- W1: h1 = tanh(h0 @ W1 + b1) via MFMA ----
  half8 a0[2];
#pragma unroll
  for (int mt = 0; mt < 2; ++mt){
    int s = wv * 64 + mt * 32 + ln31;
    a0[mt] = *(const half8*)(lds + H0_OFF + s * H0_STRIDE + khi * 16);
  }
  f32x16 d1[2][2];
#pragma unroll
  for (int mt = 0; mt < 2; ++mt)
#pragma unroll
    for (int nt = 0; nt < 2; ++nt) d1[mt][nt] = zero16();
#pragma unroll
  for (int nt = 0; nt < 2; ++nt)
#pragma unroll
    for (int mt = 0; mt < 2; ++mt)
      d1[mt][nt] = __builtin_amdgcn_mfma_f32_32x32x16_f16(a0[mt], w1f[nt], d1[mt][nt], 0, 0, 0);
#pragma unroll
  for (int mt = 0; mt < 2; ++mt)
#pragma unroll
    for (int nt = 0; nt < 2; ++nt)
#pragma unroll
      for (int i = 0; i < 16; ++i){
        int row = (i & 3) + 8 * (i >> 2) + rowbase;
        int s = wv * 64 + mt * 32 + row;
        float v = ftanh(d1[mt][nt][i] + bias1[nt]);
        *(f16*)(lds + H_OFF + s * H_STRIDE + (nt * 32 + ln31) * 2) = (f16)v;
      }

  // ---- W2: h2 = h1 @ W2 + b2 via MFMA ----
  half8 a1[2][4];
#pragma unroll
  for (int mt = 0; mt < 2; ++mt){
    int s = wv * 64 + mt * 32 + ln31;
#pragma unroll
    for (int kt = 0; kt < 4; ++kt)
      a1[mt][kt] = *(const half8*)(lds + H_OFF + s * H_STRIDE + kt * 32 + khi * 16);
  }
  f32x16 d2[2][2];
#pragma unroll
  for (int mt = 0; mt < 2; ++mt)
#pragma unroll
    for (int nt = 0; nt < 2; ++nt) d2[mt][nt] = zero16();
#pragma unroll
  for (int kt = 0; kt < 4; ++kt)
#pragma unroll
    for (int nt = 0; nt < 2; ++nt)
#pragma unroll
      for (int mt = 0; mt < 2; ++mt)
        d2[mt][nt] = __builtin_amdgcn_mfma_f32_32x32x16_f16(a1[mt][kt], w2f[kt * 2 + nt], d2[mt][nt], 0, 0, 0);

  // ---- prefetch feature u=0's Wout frags (hidden behind W2 epilogue) ----
  const half8* WOF = (const half8*)(ws + WOF_OFF);
  const float* BOF = (const float*)(ws + BOF_OFF);
  half8 bfn[4];
#pragma unroll
  for (int kt = 0; kt < 4; ++kt) bfn[kt] = WOF[((l * 8 + 0) * 4 + kt) * 64 + lane];
  float biasn = BOF[(l * 8 + 0) * 32 + ln31];

#pragma unroll
  for (int mt = 0; mt < 2; ++mt)
#pragma unroll
    for (int nt = 0; nt < 2; ++nt)
#pragma unroll
      for (int i = 0; i < 16; ++i){
        int row = (i & 3) + 8 * (i >> 2) + rowbase;
        int s = wv * 64 + mt * 32 + row;
        float v = d2[mt][nt][i] + bias2[nt];
        *(f16*)(lds + H_OFF + s * H_STRIDE + (nt * 32 + ln31) * 2) = (f16)v;
      }

  // ---- h2 A-fragments (reused across all 8 features) ----
  half8 a2[2][4];
#pragma unroll
  for (int mt = 0; mt < 2; ++mt){
    int s = wv * 64 + mt * 32 + ln31;
#pragma unroll
    for (int kt = 0; kt < 4; ++kt)
      a2[mt][kt] = *(const half8*)(lds + H_OFF + s * H_STRIDE + kt * 32 + khi * 16);
  }

  // ---- per-feature: p = h2 @ Wout_cols + bout (software-pipelined loads),
  //      transpose via LDS, spline ----
#pragma unroll 1
  for (int u = 0; u < 8; ++u){
    half8 bfc[4];
#pragma unroll
    for (int kt = 0; kt < 4; ++kt) bfc[kt] = bfn[kt];
    float biasp = biasn;
    if (u < 7){
#pragma unroll
      for (int kt = 0; kt < 4; ++kt) bfn[kt] = WOF[((l * 8 + u + 1) * 4 + kt) * 64 + lane];
      biasn = BOF[(l * 8 + u + 1) * 32 + ln31];
    }

    const int f = PAR + 2 * u;
    f32x16 dp[2];
    dp[0] = zero16(); dp[1] = zero16();
#pragma unroll
    for (int kt = 0; kt < 4; ++kt)
#pragma unroll
      for (int mt = 0; mt < 2; ++mt)
        dp[mt] = __builtin_amdgcn_mfma_f32_32x32x16_f16(a2[mt][kt], bfc[kt], dp[mt], 0, 0, 0);

    if (ln31 < 25){
#pragma unroll
      for (int mt = 0; mt < 2; ++mt)
#pragma unroll
        for (int i = 0; i < 16; ++i){
          int row = (i & 3) + 8 * (i >> 2) + rowbase;
          int s = wv * 64 + mt * 32 + row;
          *(float*)(lds + P_OFF + s * P_STRIDE + ln31 * 4) = dp[mt][i] + biasp;
        }
    }
    float p[25];
#pragma unroll
    for (int j = 0; j < 25; ++j)
      p[j] = *(const float*)(lds + P_OFF + t * P_STRIDE + j * 4);
    float y, ld;
    rq_spline(p, z[f], y, ld);
    z[f] = y;
    logdet += ld;
  }

  // ---- affine (log|scale| sum precomputed in prep) ----
  const float* scp = scv + l * 16;
  const float* shp = shv + l * 16;
#pragma unroll
  for (int j = 0; j < 16; ++j)
    z[j] = fmaf(z[j], scp[j], shp[j]);
}

extern "C" __global__ void __launch_bounds__(256, 2)
flow_kernel(const float* __restrict__ x,
            const float* __restrict__ W0, const float* __restrict__ b0,
            const float* __restrict__ b1v, const float* __restrict__ b2v,
            const float* __restrict__ scv, const float* __restrict__ shv,
            const char* __restrict__ ws, float* __restrict__ out, int B)
{
  extern __shared__ char lds[];
  const int t    = threadIdx.x;
  const int lane = t & 63;
  const int wv   = t >> 6;
  const int ln31 = lane & 31;
  const int khi  = lane >> 5;
  const int g    = blockIdx.x * 256 + t;

  float z[16];
  const float4* xv = reinterpret_cast<const float4*>(x + (size_t)g * 16);
  float4 a0 = xv[0], a1 = xv[1], a2 = xv[2], a3 = xv[3];
  z[0]=a0.x; z[1]=a0.y; z[2]=a0.z; z[3]=a0.w;
  z[4]=a1.x; z[5]=a1.y; z[6]=a1.z; z[7]=a1.w;
  z[8]=a2.x; z[9]=a2.y; z[10]=a2.z; z[11]=a2.w;
  z[12]=a3.x; z[13]=a3.y; z[14]=a3.z; z[15]=a3.w;

  float logdet = 0.f;
  for (int l = 7; l >= 0; --l){
    if (l & 1) layer_mfma<1>(l, W0, b0, b1v, b2v, scv, shv, ws, lds, z, logdet, t, lane, wv, ln31, khi);
    else       layer_mfma<0>(l, W0, b0, b1v, b2v, scv, shv, ws, lds, z, logdet, t, lane, wv, ln31, khi);
  }

  float sumlog = *(const float*)(ws + SUMLOG_OFF);
  float ss = 0.f;
#pragma unroll
  for (int j = 0; j < 16; ++j) ss = fmaf(z[j], z[j], ss);
  out[g] = -0.5f * ss - 14.7030165f + logdet + sumlog;
}

extern "C" void kernel_launch(void* const* d_in, const int* in_sizes, int n_in,
                              void* d_out, int out_size, void* d_ws, size_t ws_size,
                              hipStream_t stream)
{
  const float* x    = (const float*)d_in[0];
  const float* W0   = (const float*)d_in[1];
  const float* b0   = (const float*)d_in[2];
  const float* W1   = (const float*)d_in[3];
  const float* b1   = (const float*)d_in[4];
  const float* W2   = (const float*)d_in[5];
  const float* b2   = (const float*)d_in[6];
  const float* Wout = (const float*)d_in[7];
  const float* bout = (const float*)d_in[8];
  const float* scale= (const float*)d_in[9];
  const float* shift= (const float*)d_in[10];

  int B = in_sizes[0] / 16;

  hipLaunchKernelGGL(prep_kernel, dim3(93), dim3(256), 0, stream,
                     W1, W2, Wout, bout, scale, (char*)d_ws);

  hipLaunchKernelGGL(flow_kernel, dim3(B / 256), dim3(256), LDS_BYTES, stream,
                     x, W0, b0, b1, b2, scale, shift,
                     (const char*)d_ws, (float*)d_out, B);
}

// Round 6
// 211.032 us; speedup vs baseline: 10.4035x; 1.0075x over previous
//
#include <hip/hip_runtime.h>
#include <math.h>

typedef _Float16 f16;
typedef _Float16 half8 __attribute__((ext_vector_type(8)));
typedef float f32x16 __attribute__((ext_vector_type(16)));

#define DEV __device__ __forceinline__

// ---------------- workspace layout (bytes) ----------------
#define W1F_OFF 0        // [L][nt2]      : 16 frags  = 16 KB
#define W2F_OFF 16384    // [L][kt4][nt2] : 64 frags  = 64 KB
#define WOF_OFF 81920    // [L][u8][kt4]  : 256 frags = 256 KB (used cols, 32-padded)
#define BOF_OFF 344064   // [L][u8][32] fp32 bias for used cols = 8 KB
#define SUMLOG_OFF 352256 // 1 fp32: sum over all layers/features of log|scale|

// ---------------- LDS layout (bytes, per block of 256 samples) -------------
#define H0_OFF    0       // [256][48]  : 16 f16/sample
#define H0_STRIDE 48
#define H_OFF     12288   // [256][144] : 64 f16/sample (128+16 pad)
#define H_STRIDE  144
#define P_OFF     49152   // [256][116] : 29 fp32/sample (stride 29 dwords, conflict-free b32)
#define P_STRIDE  116
#define LDS_BYTES 78848

DEV float frcp(float x){ return __builtin_amdgcn_rcpf(x); }
DEV float fexp(float x){ return __expf(x); }
DEV float flog(float x){ return __logf(x); }

// tanh = 1 - 2/(e^{2x}+1). Robust without clamp: x→+inf: rcp(inf)=0 → 1;
// x→-inf: rcp(1)=1 → -1. 5 instructions.
DEV float ftanh(float x){
  float e = fexp(2.f * x);
  float r = frcp(e + 1.f);
  return fmaf(-2.f, r, 1.f);
}

// Rational-quadratic spline forward + log-det (fp32, per-thread).
// No softmax max-sub (|p| small), only 2 softplus (idx, idx+1),
// masked partial sum for y-knot.
DEV void rq_spline(const float p[25], float xv, float &y_out, float &ld_out)
{
  float ew[8]; float sw = 0.f;
#pragma unroll
  for (int k = 0; k < 8; ++k){ ew[k] = fexp(p[k]); sw += ew[k]; }
  float rw = frcp(sw) * 19.9992f;           // (RMAX-RMIN) - K*MIN_BIN

  float xpos[9];
  xpos[0] = -10.f;
#pragma unroll
  for (int k = 0; k < 8; ++k) xpos[k + 1] = xpos[k] + fmaf(ew[k], rw, 1e-4f);

  int idx = 0;
#pragma unroll
  for (int j = 1; j < 8; ++j) idx += (xv >= xpos[j]) ? 1 : 0;

  float xk = xpos[0], ewk = ew[0];
#pragma unroll
  for (int j = 1; j < 8; ++j){
    bool sel = (idx >= j);
    xk  = sel ? xpos[j] : xk;
    ewk = sel ? ew[j]   : ewk;
  }
  float bw = fmaf(ewk, rw, 1e-4f);

  float eh[8]; float shs = 0.f;
#pragma unroll
  for (int k = 0; k < 8; ++k){ eh[k] = fexp(p[8 + k]); shs += eh[k]; }
  float rh = frcp(shs) * 19.9992f;

  float S = 0.f, ehk = eh[0];
#pragma unroll
  for (int k = 1; k < 8; ++k){
    bool sel = (idx >= k);
    S   += sel ? eh[k - 1] : 0.f;
    ehk  = sel ? eh[k]     : ehk;
  }
  float yk = fmaf(S, rh, fmaf((float)idx, 1e-4f, -10.f));
  float bh = fmaf(ehk, rh, 1e-4f);

  float uA = p[16], uB = p[17];
#pragma unroll
  for (int j = 1; j < 8; ++j){
    bool sel = (idx >= j);
    uA = sel ? p[16 + j] : uA;
    uB = sel ? p[17 + j] : uB;
  }
  float vA = uA + 0.54116666f;
  float dk  = fmaxf(vA, 0.f) + flog(1.f + fexp(-fabsf(vA))) + 1e-4f;
  float vB = uB + 0.54116666f;
  float dk1 = fmaxf(vB, 0.f) + flog(1.f + fexp(-fabsf(vB))) + 1e-4f;

  float rbw = frcp(bw);
  float s   = bh * rbw;
  float zf  = fminf(fmaxf((xv - xk) * rbw, 0.f), 1.f);
  float z1  = 1.f - zf;
  float zz  = zf * zf, z01 = zf * z1;
  float den = s + (dk1 + dk - 2.f * s) * z01;
  float rden = frcp(den);
  float yv  = yk + bh * (s * zz + dk * z01) * rden;
  float num = dk1 * zz + 2.f * s * z01 + dk * z1 * z1;
  float ldv = flog(s * s * num * rden * rden);

  bool outside = (xv <= -10.f) || (xv >= 10.f);
  y_out  = outside ? xv : yv;
  ld_out = outside ? 0.f : ldv;
}

// ---------------- prep kernel: pack fp16 B-fragments into ws ----------------
extern "C" __global__ void __launch_bounds__(256)
prep_kernel(const float* __restrict__ W1, const float* __restrict__ W2,
            const float* __restrict__ Wo, const float* __restrict__ bout,
            const float* __restrict__ scale, char* __restrict__ ws)
{
  int tid = blockIdx.x * 256 + threadIdx.x;
  if (tid < 1024){                       // W1 frags: [L][nt2]
    int fi = tid >> 6, lane = tid & 63;
    int l = fi >> 1, nt = fi & 1;
    int n = nt * 32 + (lane & 31), khi = lane >> 5;
    half8 h;
#pragma unroll
    for (int j = 0; j < 8; ++j){ int k = khi * 8 + j; h[j] = (f16)W1[l * 1024 + k * 64 + n]; }
    *(half8*)(ws + W1F_OFF + fi * 1024 + lane * 16) = h;
  } else if (tid < 5120){                // W2 frags: [L][kt4][nt2]
    int idx = tid - 1024;
    int fi = idx >> 6, lane = idx & 63;
    int l = fi >> 3, kt = (fi >> 1) & 3, nt = fi & 1;
    int n = nt * 32 + (lane & 31), khi = lane >> 5;
    half8 h;
#pragma unroll
    for (int j = 0; j < 8; ++j){ int k = kt * 16 + khi * 8 + j; h[j] = (f16)W2[l * 4096 + k * 64 + n]; }
    *(half8*)(ws + W2F_OFF + fi * 1024 + lane * 16) = h;
  } else if (tid < 21504){               // Wout used-col frags: [L][u8][kt4]
    int idx = tid - 5120;
    int fi = idx >> 6, lane = idx & 63;
    int l = fi >> 5, u = (fi >> 2) & 7, kt = fi & 3;
    int f = (l & 1) + 2 * u;
    int c = lane & 31, khi = lane >> 5;
    half8 h;
#pragma unroll
    for (int j = 0; j < 8; ++j){
      int k = kt * 16 + khi * 8 + j;
      float v = (c < 25) ? Wo[l * 25600 + k * 400 + f * 25 + c] : 0.f;
      h[j] = (f16)v;
    }
    *(half8*)(ws + WOF_OFF + fi * 1024 + lane * 16) = h;
  } else if (tid < 23552){               // bout used cols: [L][u8][32] fp32
    int idx = tid - 21504;
    int l = idx >> 8, u = (idx >> 5) & 7, c = idx & 31;
    int f = (l & 1) + 2 * u;
    float v = (c < 25) ? bout[l * 400 + f * 25 + c] : 0.f;
    ((float*)(ws + BOF_OFF))[idx] = v;
  } else if (tid == 23552){              // sum of log|scale| over all layers
    float acc = 0.f;
    for (int i = 0; i < 128; ++i) acc += logf(fabsf(scale[i]));
    *(float*)(ws + SUMLOG_OFF) = acc;
  }
}

// ---------------- one coupling layer (all LDS traffic wave-private) --------
template<int PAR>
DEV void layer_mfma(int l,
                    const float* __restrict__ W0, const float* __restrict__ b0,
                    const float* __restrict__ b1v, const float* __restrict__ b2v,
                    const float* __restrict__ scv, const float* __restrict__ shv,
                    const char* __restrict__ ws, char* lds,
                    float (&z)[16], float &logdet,
                    int t, int lane, int wv, int ln31, int khi)
{
  const float* w0  = W0 + l * 256;
  const float* bb0 = b0 + l * 16;
  const int rowbase = khi * 4;     // C/D layout: row = (i&3)+8*(i>>2)+4*(lane>>5)

  // ---- hoisted weight-fragment loads (latency hidden behind h0 VALU) ----
  const half8* W1F = (const half8*)(ws + W1F_OFF);
  const half8* W2F = (const half8*)(ws + W2F_OFF);
  half8 w1f[2];
#pragma unroll
  for (int nt = 0; nt < 2; ++nt) w1f[nt] = W1F[(l * 2 + nt) * 64 + lane];
  half8 w2f[8];
#pragma unroll
  for (int kt = 0; kt < 4; ++kt)
#pragma unroll
    for (int nt = 0; nt < 2; ++nt)
      w2f[kt * 2 + nt] = W2F[((l * 4 + kt) * 2 + nt) * 64 + lane];
  float bias1[2], bias2[2];
#pragma unroll
  for (int nt = 0; nt < 2; ++nt){
    bias1[nt] = b1v[l * 64 + nt * 32 + ln31];
    bias2[nt] = b2v[l * 64 + nt * 32 + ln31];
  }

  // ---- h0 = tanh(mz @ W0 + b0), per-thread VALU ----
  float h0[16];
#pragma unroll
  for (int j = 0; j < 16; ++j) h0[j] = bb0[j];
#pragma unroll
  for (int u = 0; u < 8; ++u){
    const int f = (1 - PAR) + 2 * u;
    const float v = z[f];
#pragma unroll
    for (int j = 0; j < 16; ++j) h0[j] = fmaf(v, w0[f * 16 + j], h0[j]);
  }
  {
    half8 lo, hi;
#pragma unroll
    for (int j = 0; j < 8; ++j){ lo[j] = (f16)ftanh(h0[j]); hi[j] = (f16)ftanh(h0[8 + j]); }
    *(half8*)(lds + H0_OFF + t * H0_STRIDE)      = lo;
    *(half8*)(lds + H0_OFF + t * H0_STRIDE + 16) = hi;
  }

  // ---- W1: h1 = tanh(h0 @ W1 + b1) via MFMA (bias folded into acc init) ----
  half8 a0[2];
#pragma unroll
  for (int mt = 0; mt < 2; ++mt){
    int s = wv * 64 + mt * 32 + ln31;
    a0[mt] = *(const half8*)(lds + H0_OFF + s * H0_STRIDE + khi * 16);
  }
  f32x16 d1[2][2];
#pragma unroll
  for (int mt = 0; mt < 2; ++mt)
#pragma unroll
    for (int nt = 0; nt < 2; ++nt)
#pragma unroll
      for (int i = 0; i < 16; ++i) d1[mt][nt][i] = bias1[nt];
#pragma unroll
  for (int nt = 0; nt < 2; ++nt)
#pragma unroll
    for (int mt = 0; mt < 2; ++mt)
      d1[mt][nt] = __builtin_amdgcn_mfma_f32_32x32x16_f16(a0[mt], w1f[nt], d1[mt][nt], 0, 0, 0);
#pragma unroll
  for (int mt = 0; mt < 2; ++mt)
#pragma unroll
    for (int nt = 0; nt < 2; ++nt)
#pragma unroll
      for (int i = 0; i < 16; ++i){
        int row = (i & 3) + 8 * (i >> 2) + rowbase;
        int s = wv * 64 + mt * 32 + row;
        float v = ftanh(d1[mt][nt][i]);
        *(f16*)(lds + H_OFF + s * H_STRIDE + (nt * 32 + ln31) * 2) = (f16)v;
      }

  // ---- W2: h2 = h1 @ W2 + b2 via MFMA (bias folded) ----
  half8 a1[2][4];
#pragma unroll
  for (int mt = 0; mt < 2; ++mt){
    int s = wv * 64 + mt * 32 + ln31;
#pragma unroll
    for (int kt = 0; kt < 4; ++kt)
      a1[mt][kt] = *(const half8*)(lds + H_OFF + s * H_STRIDE + kt * 32 + khi * 16);
  }
  f32x16 d2[2][2];
#pragma unroll
  for (int mt = 0; mt < 2; ++mt)
#pragma unroll
    for (int nt = 0; nt < 2; ++nt)
#pragma unroll
      for (int i = 0; i < 16; ++i) d2[mt][nt][i] = bias2[nt];
#pragma unroll
  for (int kt = 0; kt < 4; ++kt)
#pragma unroll
    for (int nt = 0; nt < 2; ++nt)
#pragma unroll
      for (int mt = 0; mt < 2; ++mt)
        d2[mt][nt] = __builtin_amdgcn_mfma_f32_32x32x16_f16(a1[mt][kt], w2f[kt * 2 + nt], d2[mt][nt], 0, 0, 0);

  // ---- prefetch feature u=0's Wout frags (hidden behind W2 epilogue) ----
  const half8* WOF = (const half8*)(ws + WOF_OFF);
  const float* BOF = (const float*)(ws + BOF_OFF);
  half8 bfn[4];
#pragma unroll
  for (int kt = 0; kt < 4; ++kt) bfn[kt] = WOF[((l * 8 + 0) * 4 + kt) * 64 + lane];
  float biasn = BOF[(l * 8 + 0) * 32 + ln31];

#pragma unroll
  for (int mt = 0; mt < 2; ++mt)
#pragma unroll
    for (int nt = 0; nt < 2; ++nt)
#pragma unroll
      for (int i = 0; i < 16; ++i){
        int row = (i & 3) + 8 * (i >> 2) + rowbase;
        int s = wv * 64 + mt * 32 + row;
        float v = d2[mt][nt][i];
        *(f16*)(lds + H_OFF + s * H_STRIDE + (nt * 32 + ln31) * 2) = (f16)v;
      }

  // ---- h2 A-fragments (reused across all 8 features) ----
  half8 a2[2][4];
#pragma unroll
  for (int mt = 0; mt < 2; ++mt){
    int s = wv * 64 + mt * 32 + ln31;
#pragma unroll
    for (int kt = 0; kt < 4; ++kt)
      a2[mt][kt] = *(const half8*)(lds + H_OFF + s * H_STRIDE + kt * 32 + khi * 16);
  }

  // ---- feature-loop software pipeline ----
  // Stage: p_{u+1} MFMA + LDS-store issued BEFORE spline(u); the spline's
  // long VALU chain hides the entire next-feature LDS round trip. Single
  // p-slot is safe: per-wave DS ops execute in program order, so reads of
  // p_u precede the stores of p_{u+1}.
  {
    f32x16 dp[2];
#pragma unroll
    for (int mt = 0; mt < 2; ++mt)
#pragma unroll
      for (int i = 0; i < 16; ++i) dp[mt][i] = biasn;
#pragma unroll
    for (int kt = 0; kt < 4; ++kt)
#pragma unroll
      for (int mt = 0; mt < 2; ++mt)
        dp[mt] = __builtin_amdgcn_mfma_f32_32x32x16_f16(a2[mt][kt], bfn[kt], dp[mt], 0, 0, 0);
    if (ln31 < 25){
#pragma unroll
      for (int mt = 0; mt < 2; ++mt)
#pragma unroll
        for (int i = 0; i < 16; ++i){
          int row = (i & 3) + 8 * (i >> 2) + rowbase;
          int s = wv * 64 + mt * 32 + row;
          *(float*)(lds + P_OFF + s * P_STRIDE + ln31 * 4) = dp[mt][i];
        }
    }
  }
#pragma unroll
  for (int kt = 0; kt < 4; ++kt) bfn[kt] = WOF[((l * 8 + 1) * 4 + kt) * 64 + lane];
  biasn = BOF[(l * 8 + 1) * 32 + ln31];

#pragma unroll 1
  for (int u = 0; u < 8; ++u){
    // read own sample's p for feature u
    float p[25];
#pragma unroll
    for (int j = 0; j < 25; ++j)
      p[j] = *(const float*)(lds + P_OFF + t * P_STRIDE + j * 4);

    // issue next feature's MFMA + store before the spline
    if (u < 7){
      f32x16 dp[2];
#pragma unroll
      for (int mt = 0; mt < 2; ++mt)
#pragma unroll
        for (int i = 0; i < 16; ++i) dp[mt][i] = biasn;
#pragma unroll
      for (int kt = 0; kt < 4; ++kt)
#pragma unroll
        for (int mt = 0; mt < 2; ++mt)
          dp[mt] = __builtin_amdgcn_mfma_f32_32x32x16_f16(a2[mt][kt], bfn[kt], dp[mt], 0, 0, 0);
      if (ln31 < 25){
#pragma unroll
        for (int mt = 0; mt < 2; ++mt)
#pragma unroll
          for (int i = 0; i < 16; ++i){
            int row = (i & 3) + 8 * (i >> 2) + rowbase;
            int s = wv * 64 + mt * 32 + row;
            *(float*)(lds + P_OFF + s * P_STRIDE + ln31 * 4) = dp[mt][i];
          }
      }
      if (u < 6){
#pragma unroll
        for (int kt = 0; kt < 4; ++kt) bfn[kt] = WOF[((l * 8 + u + 2) * 4 + kt) * 64 + lane];
        biasn = BOF[(l * 8 + u + 2) * 32 + ln31];
      }
    }

    const int f = PAR + 2 * u;
    float y, ld;
    rq_spline(p, z[f], y, ld);
    z[f] = y;
    logdet += ld;
  }

  // ---- affine (log|scale| sum precomputed in prep) ----
  const float* scp = scv + l * 16;
  const float* shp = shv + l * 16;
#pragma unroll
  for (int j = 0; j < 16; ++j)
    z[j] = fmaf(z[j], scp[j], shp[j]);
}

extern "C" __global__ void __launch_bounds__(256, 2)
flow_kernel(const float* __restrict__ x,
            const float* __restrict__ W0, const float* __restrict__ b0,
            const float* __restrict__ b1v, const float* __restrict__ b2v,
            const float* __restrict__ scv, const float* __restrict__ shv,
            const char* __restrict__ ws, float* __restrict__ out, int B)
{
  extern __shared__ char lds[];
  const int t    = threadIdx.x;
  const int lane = t & 63;
  const int wv   = t >> 6;
  const int ln31 = lane & 31;
  const int khi  = lane >> 5;
  const int g    = blockIdx.x * 256 + t;

  float z[16];
  const float4* xv = reinterpret_cast<const float4*>(x + (size_t)g * 16);
  float4 a0 = xv[0], a1 = xv[1], a2 = xv[2], a3 = xv[3];
  z[0]=a0.x; z[1]=a0.y; z[2]=a0.z; z[3]=a0.w;
  z[4]=a1.x; z[5]=a1.y; z[6]=a1.z; z[7]=a1.w;
  z[8]=a2.x; z[9]=a2.y; z[10]=a2.z; z[11]=a2.w;
  z[12]=a3.x; z[13]=a3.y; z[14]=a3.z; z[15]=a3.w;

  float logdet = 0.f;
  for (int l = 7; l >= 0; --l){
    if (l & 1) layer_mfma<1>(l, W0, b0, b1v, b2v, scv, shv, ws, lds, z, logdet, t, lane, wv, ln31, khi);
    else       layer_mfma<0>(l, W0, b0, b1v, b2v, scv, shv, ws, lds, z, logdet, t, lane, wv, ln31, khi);
  }

  float sumlog = *(const float*)(ws + SUMLOG_OFF);
  float ss = 0.f;
#pragma unroll
  for (int j = 0; j < 16; ++j) ss = fmaf(z[j], z[j], ss);
  out[g] = -0.5f * ss - 14.7030165f + logdet + sumlog;
}

extern "C" void kernel_launch(void* const* d_in, const int* in_sizes, int n_in,
                              void* d_out, int out_size, void* d_ws, size_t ws_size,
                              hipStream_t stream)
{
  const float* x    = (const float*)d_in[0];
  const float* W0   = (const float*)d_in[1];
  const float* b0   = (const float*)d_in[2];
  const float* W1   = (const float*)d_in[3];
  const float* b1   = (const float*)d_in[4];
  const float* W2   = (const float*)d_in[5];
  const float* b2   = (const float*)d_in[6];
  const float* Wout = (const float*)d_in[7];
  const float* bout = (const float*)d_in[8];
  const float* scale= (const float*)d_in[9];
  const float* shift= (const float*)d_in[10];

  int B = in_sizes[0] / 16;

  hipLaunchKernelGGL(prep_kernel, dim3(93), dim3(256), 0, stream,
                     W1, W2, Wout, bout, scale, (char*)d_ws);

  hipLaunchKernelGGL(flow_kernel, dim3(B / 256), dim3(256), LDS_BYTES, stream,
                     x, W0, b0, b1, b2, scale, shift,
                     (const char*)d_ws, (float*)d_out, B);
}